// Round 4
// baseline (505.338 us; speedup 1.0000x reference)
//
#include <hip/hip_runtime.h>
#include <hip/hip_bf16.h>

// Sizes (fixed by the problem)
#define B_ 4
#define N_ 1024
#define H_ 128
#define F_ 128
#define E_ 16
#define G_ 128
#define O_ 128
#define DIN 256  // F+H

// ---------------------------------------------------------------------------
// Kernel 1: att1[b,n] = feat(b,n)·w_a1 + b_a1 ; att2 likewise ; att_g[b]
// feat(b,n) = concat(n_features[b,n,:], hidden[b,n,:])
// Grid: 1024 blocks x 256 thr (4 waves = 4 rows each) + 1 extra block for att_g
// ---------------------------------------------------------------------------
__global__ __launch_bounds__(256) void k_att(
    const float* __restrict__ nf, const float* __restrict__ hid,
    const float* __restrict__ wa1, const float* __restrict__ ba1,
    const float* __restrict__ wa2, const float* __restrict__ ba2,
    const float* __restrict__ gf, const float* __restrict__ wag,
    const float* __restrict__ bag,
    float* __restrict__ att1, float* __restrict__ att2, float* __restrict__ attg) {
  const int t = threadIdx.x;
  const int w = t >> 6;
  const int lane = t & 63;

  if (blockIdx.x == (N_ * B_) / 4) {  // last block: att_g (4 batches, wave per batch)
    if (w < B_) {
      const int b = w;
      float2 g2 = *reinterpret_cast<const float2*>(gf + b * G_ + lane * 2);
      float2 wg = *reinterpret_cast<const float2*>(wag + lane * 2);
      float p = g2.x * wg.x + g2.y * wg.y;
      #pragma unroll
      for (int off = 32; off; off >>= 1) p += __shfl_xor(p, off);
      if (lane == 0) attg[b] = p + bag[0];
    }
    return;
  }

  const int g = blockIdx.x * 4 + w;  // global row 0..4095
  const int c = lane * 4;            // 64 lanes x 4 floats = 256 = DIN
  const float* src = (c < F_) ? (nf + (size_t)g * F_ + c)
                              : (hid + (size_t)g * H_ + (c - F_));
  float4 f = *reinterpret_cast<const float4*>(src);
  float4 w1 = *reinterpret_cast<const float4*>(wa1 + c);
  float4 w2 = *reinterpret_cast<const float4*>(wa2 + c);
  float p1 = f.x * w1.x + f.y * w1.y + f.z * w1.z + f.w * w1.w;
  float p2 = f.x * w2.x + f.y * w2.y + f.z * w2.z + f.w * w2.w;
  #pragma unroll
  for (int off = 32; off; off >>= 1) {
    p1 += __shfl_xor(p1, off);
    p2 += __shfl_xor(p2, off);
  }
  if (lane == 0) {
    att1[g] = p1 + ba1[0];
    att2[g] = p2 + ba2[0];
  }
}

// ---------------------------------------------------------------------------
// Kernel 2: values = feat @ W_m + b_m  (to workspace)
//           skip   = feat @ W_skip + b_skip (written straight into d_out)
// Tile: 16 rows per block, 256 blocks. Threads 0..127 -> W_m cols,
// 128..255 -> W_skip cols. feat tile staged in LDS as float4[16][64].
// ---------------------------------------------------------------------------
__global__ __launch_bounds__(256) void k_gemm(
    const float* __restrict__ nf, const float* __restrict__ hid,
    const float* __restrict__ Wm, const float* __restrict__ bm,
    const float* __restrict__ Wsk, const float* __restrict__ bsk,
    float* __restrict__ values, float* __restrict__ out) {
  __shared__ float4 feat[16][64];  // [row][k4] : 16 KB
  const int t = threadIdx.x;
  const int g0 = blockIdx.x * 16;

  #pragma unroll
  for (int q = 0; q < 4; ++q) {
    int flat = q * 256 + t;        // 0..1023 float4 slots
    int r = flat >> 6;
    int c4 = flat & 63;
    int g = g0 + r;
    int c = c4 * 4;
    const float* src = (c < F_) ? (nf + (size_t)g * F_ + c)
                                : (hid + (size_t)g * H_ + (c - F_));
    feat[r][c4] = *reinterpret_cast<const float4*>(src);
  }
  __syncthreads();

  const int col = t & 127;
  const float* W = (t < 128) ? Wm : Wsk;
  const float bias = (t < 128) ? bm[col] : bsk[col];

  float acc[16];
  #pragma unroll
  for (int r = 0; r < 16; ++r) acc[r] = 0.f;

  for (int k4 = 0; k4 < 64; ++k4) {
    float w0 = W[(k4 * 4 + 0) * O_ + col];
    float w1 = W[(k4 * 4 + 1) * O_ + col];
    float w2 = W[(k4 * 4 + 2) * O_ + col];
    float w3 = W[(k4 * 4 + 3) * O_ + col];
    #pragma unroll
    for (int r = 0; r < 16; ++r) {
      float4 f = feat[r][k4];
      acc[r] = fmaf(f.x, w0, acc[r]);
      acc[r] = fmaf(f.y, w1, acc[r]);
      acc[r] = fmaf(f.z, w2, acc[r]);
      acc[r] = fmaf(f.w, w3, acc[r]);
    }
  }

  #pragma unroll
  for (int r = 0; r < 16; ++r) {
    size_t idx = (size_t)(g0 + r) * O_ + col;
    if (t < 128) values[idx] = acc[r] + bias;
    else         out[idx]    = acc[r] + bias;
  }
}

// ---------------------------------------------------------------------------
// Kernel 3: per (b, row-tile of 8): att_e dot + logits + masked softmax + PV
// 512 blocks x 512 threads (8 waves). Wave w owns row i0+w end-to-end.
// ---------------------------------------------------------------------------
__global__ __launch_bounds__(512) void k_main(
    const float* __restrict__ ef, const float* __restrict__ adj,
    const float* __restrict__ wae, const float* __restrict__ bae,
    const float* __restrict__ att1, const float* __restrict__ att2,
    const float* __restrict__ attg,
    const float* __restrict__ values, float* __restrict__ out) {
  __shared__ float att2_s[N_];
  __shared__ float p_s[8][N_];

  const int t = threadIdx.x;
  const int w = t >> 6;
  const int lane = t & 63;
  const int b = blockIdx.x >> 7;     // 128 tiles per batch
  const int tile = blockIdx.x & 127;
  const int i0 = tile * 8;
  const int i = i0 + w;

  // stage att2[b,:] (1024 floats, 512 threads x 2)
  att2_s[t]       = att2[b * N_ + t];
  att2_s[t + 512] = att2[b * N_ + t + 512];
  __syncthreads();

  const float base = att1[b * N_ + i] + attg[b] + bae[0];
  const float4 we = *reinterpret_cast<const float4*>(wae + (lane & 3) * 4);
  const float4* erow =
      reinterpret_cast<const float4*>(ef + ((size_t)(b * N_ + i) * N_) * E_);
  const float* arow = adj + (size_t)(b * N_ + i) * N_;

  // Phase 1: logits (lrelu + mask) into LDS, tracking running max.
  float mmax = -3.0e38f;
  for (int k = 0; k < 64; ++k) {
    float4 e = erow[k * 64 + lane];  // coalesced 1KB/wave
    float part = e.x * we.x + e.y * we.y + e.z * we.z + e.w * we.w;
    part += __shfl_xor(part, 1);
    part += __shfl_xor(part, 2);     // 4-lane group now holds full dot-16
    int j = k * 16 + (lane >> 2);
    float l = base + att2_s[j] + part;
    l = (l >= 0.f) ? l : 0.01f * l;          // leaky_relu(0.01)
    l += (arow[j] - 1.0f) * 1e9f;            // bias_mat (exact as reference)
    mmax = fmaxf(mmax, l);
    if ((lane & 3) == 0) p_s[w][j] = l;
  }
  #pragma unroll
  for (int off = 32; off; off >>= 1) mmax = fmaxf(mmax, __shfl_xor(mmax, off));

  // Phase 2: exp + sum (masked entries underflow to exactly 0, same as ref)
  float s = 0.f;
  #pragma unroll 4
  for (int q = 0; q < 16; ++q) {
    int j = q * 64 + lane;
    float p = __expf(p_s[w][j] - mmax);
    p_s[w][j] = p;
    s += p;
  }
  #pragma unroll
  for (int off = 32; off; off >>= 1) s += __shfl_xor(s, off);
  const float rs = 1.0f / s;   // every lane has it (xor-reduce)

  // Phase 3: PV matvec. lanes split: jo = j-parity, 32 lanes x float4 = 128 cols.
  const int jo = lane >> 5;
  const int o4 = (lane & 31) * 4;
  const float4* vb = reinterpret_cast<const float4*>(values + (size_t)b * N_ * O_);
  float4 acc = make_float4(0.f, 0.f, 0.f, 0.f);
  #pragma unroll 4
  for (int j = 0; j < N_; j += 2) {
    float pv = p_s[w][j + jo];                    // LDS broadcast (2 addrs/wave)
    float4 v = vb[(size_t)(j + jo) * 32 + (lane & 31)];  // coalesced 1KB/wave
    acc.x = fmaf(pv, v.x, acc.x);
    acc.y = fmaf(pv, v.y, acc.y);
    acc.z = fmaf(pv, v.z, acc.z);
    acc.w = fmaf(pv, v.w, acc.w);
  }
  acc.x += __shfl_xor(acc.x, 32);
  acc.y += __shfl_xor(acc.y, 32);
  acc.z += __shfl_xor(acc.z, 32);
  acc.w += __shfl_xor(acc.w, 32);

  if (jo == 0) {
    size_t oidx = ((size_t)(b * N_ + i) * O_) + o4;
    float4 cur = *reinterpret_cast<const float4*>(out + oidx);  // skip term
    cur.x += acc.x * rs;
    cur.y += acc.y * rs;
    cur.z += acc.z * rs;
    cur.w += acc.w * rs;
    *reinterpret_cast<float4*>(out + oidx) = cur;
  }
}

// ---------------------------------------------------------------------------
extern "C" void kernel_launch(void* const* d_in, const int* in_sizes, int n_in,
                              void* d_out, int out_size, void* d_ws, size_t ws_size,
                              hipStream_t stream) {
  const float* hidden = (const float*)d_in[0];
  const float* nf     = (const float*)d_in[1];
  const float* ef     = (const float*)d_in[2];
  const float* gf     = (const float*)d_in[3];
  const float* adj    = (const float*)d_in[4];
  const float* Wm     = (const float*)d_in[5];
  const float* bm     = (const float*)d_in[6];
  const float* Wsk    = (const float*)d_in[7];
  const float* bsk    = (const float*)d_in[8];
  const float* wa1    = (const float*)d_in[9];
  const float* ba1    = (const float*)d_in[10];
  const float* wa2    = (const float*)d_in[11];
  const float* ba2    = (const float*)d_in[12];
  const float* wae    = (const float*)d_in[13];
  const float* bae    = (const float*)d_in[14];
  const float* wag    = (const float*)d_in[15];
  const float* bag    = (const float*)d_in[16];

  float* out = (float*)d_out;
  float* ws = (float*)d_ws;
  float* values = ws;                       // 4*1024*128 = 524288 floats
  float* att1v  = ws + 524288;              // 4096
  float* att2v  = ws + 528384;              // 4096
  float* attgv  = ws + 532480;              // 4

  hipLaunchKernelGGL(k_att, dim3(N_ * B_ / 4 + 1), dim3(256), 0, stream,
                     nf, hidden, wa1, ba1, wa2, ba2, gf, wag, bag,
                     att1v, att2v, attgv);
  hipLaunchKernelGGL(k_gemm, dim3(B_ * N_ / 16), dim3(256), 0, stream,
                     nf, hidden, Wm, bm, Wsk, bsk, values, out);
  hipLaunchKernelGGL(k_main, dim3(B_ * N_ / 8), dim3(512), 0, stream,
                     ef, adj, wae, bae, att1v, att2v, attgv, values, out);
}

// Round 5
// 428.679 us; speedup vs baseline: 1.1788x; 1.1788x over previous
//
#include <hip/hip_runtime.h>
#include <hip/hip_bf16.h>

// Sizes (fixed by the problem)
#define B_ 4
#define N_ 1024
#define H_ 128
#define F_ 128
#define E_ 16
#define G_ 128
#define O_ 128
#define DIN 256  // F+H

// ---------------------------------------------------------------------------
// Kernel 1: att1[b,n] = feat(b,n)·w_a1 + b_a1 ; att2 likewise ; att_g[b]
// ---------------------------------------------------------------------------
__global__ __launch_bounds__(256) void k_att(
    const float* __restrict__ nf, const float* __restrict__ hid,
    const float* __restrict__ wa1, const float* __restrict__ ba1,
    const float* __restrict__ wa2, const float* __restrict__ ba2,
    const float* __restrict__ gf, const float* __restrict__ wag,
    const float* __restrict__ bag,
    float* __restrict__ att1, float* __restrict__ att2, float* __restrict__ attg) {
  const int t = threadIdx.x;
  const int w = t >> 6;
  const int lane = t & 63;

  if (blockIdx.x == (N_ * B_) / 4) {  // last block: att_g (wave per batch)
    if (w < B_) {
      const int b = w;
      float2 g2 = *reinterpret_cast<const float2*>(gf + b * G_ + lane * 2);
      float2 wg = *reinterpret_cast<const float2*>(wag + lane * 2);
      float p = g2.x * wg.x + g2.y * wg.y;
      #pragma unroll
      for (int off = 32; off; off >>= 1) p += __shfl_xor(p, off);
      if (lane == 0) attg[b] = p + bag[0];
    }
    return;
  }

  const int g = blockIdx.x * 4 + w;  // global row 0..4095
  const int c = lane * 4;            // 64 lanes x 4 floats = 256 = DIN
  const float* src = (c < F_) ? (nf + (size_t)g * F_ + c)
                              : (hid + (size_t)g * H_ + (c - F_));
  float4 f = *reinterpret_cast<const float4*>(src);
  float4 w1 = *reinterpret_cast<const float4*>(wa1 + c);
  float4 w2 = *reinterpret_cast<const float4*>(wa2 + c);
  float p1 = f.x * w1.x + f.y * w1.y + f.z * w1.z + f.w * w1.w;
  float p2 = f.x * w2.x + f.y * w2.y + f.z * w2.z + f.w * w2.w;
  #pragma unroll
  for (int off = 32; off; off >>= 1) {
    p1 += __shfl_xor(p1, off);
    p2 += __shfl_xor(p2, off);
  }
  if (lane == 0) {
    att1[g] = p1 + ba1[0];
    att2[g] = p2 + ba2[0];
  }
}

// ---------------------------------------------------------------------------
// Kernel 2: values = feat @ W_m + b_m ; skip = feat @ W_skip + b_skip (-> out)
// 8 rows/block, 512 blocks (2 blocks/CU).
// ---------------------------------------------------------------------------
__global__ __launch_bounds__(256) void k_gemm(
    const float* __restrict__ nf, const float* __restrict__ hid,
    const float* __restrict__ Wm, const float* __restrict__ bm,
    const float* __restrict__ Wsk, const float* __restrict__ bsk,
    float* __restrict__ values, float* __restrict__ out) {
  __shared__ float4 feat[8][64];  // [row][k4] : 8 KB
  const int t = threadIdx.x;
  const int g0 = blockIdx.x * 8;

  #pragma unroll
  for (int q = 0; q < 2; ++q) {
    int flat = q * 256 + t;        // 0..511 float4 slots
    int r = flat >> 6;
    int c4 = flat & 63;
    int g = g0 + r;
    int c = c4 * 4;
    const float* src = (c < F_) ? (nf + (size_t)g * F_ + c)
                                : (hid + (size_t)g * H_ + (c - F_));
    feat[r][c4] = *reinterpret_cast<const float4*>(src);
  }
  __syncthreads();

  const int col = t & 127;
  const float* W = (t < 128) ? Wm : Wsk;
  const float bias = (t < 128) ? bm[col] : bsk[col];

  float acc[8];
  #pragma unroll
  for (int r = 0; r < 8; ++r) acc[r] = 0.f;

  #pragma unroll 2
  for (int k4 = 0; k4 < 64; ++k4) {
    float w0 = W[(k4 * 4 + 0) * O_ + col];
    float w1 = W[(k4 * 4 + 1) * O_ + col];
    float w2 = W[(k4 * 4 + 2) * O_ + col];
    float w3 = W[(k4 * 4 + 3) * O_ + col];
    #pragma unroll
    for (int r = 0; r < 8; ++r) {
      float4 f = feat[r][k4];
      acc[r] = fmaf(f.x, w0, acc[r]);
      acc[r] = fmaf(f.y, w1, acc[r]);
      acc[r] = fmaf(f.z, w2, acc[r]);
      acc[r] = fmaf(f.w, w3, acc[r]);
    }
  }

  #pragma unroll
  for (int r = 0; r < 8; ++r) {
    size_t idx = (size_t)(g0 + r) * O_ + col;
    if (t < 128) values[idx] = acc[r] + bias;
    else         out[idx]    = acc[r] + bias;
  }
}

// ---------------------------------------------------------------------------
// Kernel 3: per (b, 8-row tile): e-dot -> logits -> softmax -> PV + reduce.
// 512 blocks x 512 threads (8 waves).
//  P1: wave w computes e-dot for row i0+w (8 loads in flight).
//  P2: wave w finishes logits in registers, normalizes, stores p to LDS.
//  P3: wave w applies j-slice [w*128,(w+1)*128) to ALL 8 rows (V read once
//      per block), cross-wave reduce via LDS (p_s reused for partials).
// ---------------------------------------------------------------------------
__global__ __launch_bounds__(512) void k_main(
    const float* __restrict__ ef, const float* __restrict__ adj,
    const float* __restrict__ wae, const float* __restrict__ bae,
    const float* __restrict__ att1, const float* __restrict__ att2,
    const float* __restrict__ attg,
    const float* __restrict__ values, float* __restrict__ out) {
  __shared__ float att2_s[N_];
  __shared__ float p_s[8][N_];   // e-dot -> normalized p -> PV partials

  const int t = threadIdx.x;
  const int w = t >> 6;
  const int lane = t & 63;
  const int b = blockIdx.x >> 7;
  const int tile = blockIdx.x & 127;
  const int i0 = tile * 8;
  const int i = i0 + w;

  att2_s[t]       = att2[b * N_ + t];
  att2_s[t + 512] = att2[b * N_ + t + 512];
  __syncthreads();

  // ---- Phase 1: e-dot only, deep ILP (8 x 1KB wave-loads in flight) ----
  const float4 we = *reinterpret_cast<const float4*>(wae + (lane & 3) * 4);
  const float4* erow =
      reinterpret_cast<const float4*>(ef + ((size_t)(b * N_ + i) * N_) * E_);
  for (int kk = 0; kk < 64; kk += 8) {
    float4 e[8];
    #pragma unroll
    for (int u = 0; u < 8; ++u) e[u] = erow[(kk + u) * 64 + lane];
    #pragma unroll
    for (int u = 0; u < 8; ++u) {
      float part = e[u].x * we.x + e[u].y * we.y + e[u].z * we.z + e[u].w * we.w;
      part += __shfl_xor(part, 1);
      part += __shfl_xor(part, 2);   // 4-lane group holds full dot-16
      if ((lane & 3) == 0) p_s[w][(kk + u) * 16 + (lane >> 2)] = part;
    }
  }

  // ---- Phase 2: finish logits in registers, softmax, store normalized p ----
  const float base = att1[b * N_ + i] + attg[b] + bae[0];
  const float4* adj4 =
      reinterpret_cast<const float4*>(adj + (size_t)(b * N_ + i) * N_);
  float4 la[4];
  float vmax = -3.0e38f;
  #pragma unroll
  for (int q = 0; q < 4; ++q) {
    int j4 = q * 64 + lane;   // float4 index; j = j4*4..j4*4+3
    float4 p4 = *reinterpret_cast<const float4*>(&p_s[w][j4 * 4]);
    float4 a4 = adj4[j4];
    float4 t2 = *reinterpret_cast<const float4*>(&att2_s[j4 * 4]);
    float4 l;
    l.x = base + t2.x + p4.x; l.x = (l.x >= 0.f) ? l.x : 0.01f * l.x; l.x += (a4.x - 1.f) * 1e9f;
    l.y = base + t2.y + p4.y; l.y = (l.y >= 0.f) ? l.y : 0.01f * l.y; l.y += (a4.y - 1.f) * 1e9f;
    l.z = base + t2.z + p4.z; l.z = (l.z >= 0.f) ? l.z : 0.01f * l.z; l.z += (a4.z - 1.f) * 1e9f;
    l.w = base + t2.w + p4.w; l.w = (l.w >= 0.f) ? l.w : 0.01f * l.w; l.w += (a4.w - 1.f) * 1e9f;
    la[q] = l;
    vmax = fmaxf(vmax, fmaxf(fmaxf(l.x, l.y), fmaxf(l.z, l.w)));
  }
  #pragma unroll
  for (int off = 32; off; off >>= 1) vmax = fmaxf(vmax, __shfl_xor(vmax, off));

  float s = 0.f;
  #pragma unroll
  for (int q = 0; q < 4; ++q) {
    la[q].x = __expf(la[q].x - vmax);
    la[q].y = __expf(la[q].y - vmax);
    la[q].z = __expf(la[q].z - vmax);
    la[q].w = __expf(la[q].w - vmax);
    s += la[q].x + la[q].y + la[q].z + la[q].w;
  }
  #pragma unroll
  for (int off = 32; off; off >>= 1) s += __shfl_xor(s, off);
  const float rs = 1.0f / s;
  #pragma unroll
  for (int q = 0; q < 4; ++q) {
    float4 p;
    p.x = la[q].x * rs; p.y = la[q].y * rs; p.z = la[q].z * rs; p.w = la[q].w * rs;
    *reinterpret_cast<float4*>(&p_s[w][(q * 64 + lane) * 4]) = p;
  }
  __syncthreads();   // all p rows visible to all waves

  // ---- Phase 3: wave w covers j-slice for all 8 rows; V read once/block ----
  const int jo = lane >> 5;          // half-wave j offset
  const int l31 = lane & 31;
  const float4* vb = reinterpret_cast<const float4*>(values + (size_t)b * N_ * O_);
  float4 acc[8];
  #pragma unroll
  for (int r = 0; r < 8; ++r) acc[r] = make_float4(0.f, 0.f, 0.f, 0.f);

  const int jbase = w * 128;
  #pragma unroll 4
  for (int it = 0; it < 64; ++it) {
    int jj = jbase + it * 2 + jo;
    float4 v = vb[(size_t)jj * 32 + l31];   // 1KB/wave, L2-resident
    #pragma unroll
    for (int r = 0; r < 8; ++r) {
      float pv = p_s[r][jj];                // 2-addr LDS broadcast
      acc[r].x = fmaf(pv, v.x, acc[r].x);
      acc[r].y = fmaf(pv, v.y, acc[r].y);
      acc[r].z = fmaf(pv, v.z, acc[r].z);
      acc[r].w = fmaf(pv, v.w, acc[r].w);
    }
  }
  // fold the two half-wave j-subsets
  #pragma unroll
  for (int r = 0; r < 8; ++r) {
    acc[r].x += __shfl_xor(acc[r].x, 32);
    acc[r].y += __shfl_xor(acc[r].y, 32);
    acc[r].z += __shfl_xor(acc[r].z, 32);
    acc[r].w += __shfl_xor(acc[r].w, 32);
  }
  __syncthreads();   // everyone done reading p_s

  // store partials: part[w][r][128] into p_s storage (8*8*128 = 8192 floats)
  float* part = &p_s[0][0];
  if (jo == 0) {
    #pragma unroll
    for (int r = 0; r < 8; ++r)
      *reinterpret_cast<float4*>(part + (w * 8 + r) * 128 + l31 * 4) = acc[r];
  }
  __syncthreads();

  // final reduce: wave w sums 8 slice-partials for row i = i0+w.
  // half-wave jo handles source waves jo*4..jo*4+3, fold via shfl 32.
  float4 sum = make_float4(0.f, 0.f, 0.f, 0.f);
  #pragma unroll
  for (int u = 0; u < 4; ++u) {
    int wsrc = jo * 4 + u;
    float4 p = *reinterpret_cast<const float4*>(part + (wsrc * 8 + w) * 128 + l31 * 4);
    sum.x += p.x; sum.y += p.y; sum.z += p.z; sum.w += p.w;
  }
  sum.x += __shfl_xor(sum.x, 32);
  sum.y += __shfl_xor(sum.y, 32);
  sum.z += __shfl_xor(sum.z, 32);
  sum.w += __shfl_xor(sum.w, 32);

  if (jo == 0) {
    size_t oidx = ((size_t)(b * N_ + i) * O_) + l31 * 4;
    float4 cur = *reinterpret_cast<const float4*>(out + oidx);  // skip term
    cur.x += sum.x; cur.y += sum.y; cur.z += sum.z; cur.w += sum.w;
    *reinterpret_cast<float4*>(out + oidx) = cur;
  }
}

// ---------------------------------------------------------------------------
extern "C" void kernel_launch(void* const* d_in, const int* in_sizes, int n_in,
                              void* d_out, int out_size, void* d_ws, size_t ws_size,
                              hipStream_t stream) {
  const float* hidden = (const float*)d_in[0];
  const float* nf     = (const float*)d_in[1];
  const float* ef     = (const float*)d_in[2];
  const float* gf     = (const float*)d_in[3];
  const float* adj    = (const float*)d_in[4];
  const float* Wm     = (const float*)d_in[5];
  const float* bm     = (const float*)d_in[6];
  const float* Wsk    = (const float*)d_in[7];
  const float* bsk    = (const float*)d_in[8];
  const float* wa1    = (const float*)d_in[9];
  const float* ba1    = (const float*)d_in[10];
  const float* wa2    = (const float*)d_in[11];
  const float* ba2    = (const float*)d_in[12];
  const float* wae    = (const float*)d_in[13];
  const float* bae    = (const float*)d_in[14];
  const float* wag    = (const float*)d_in[15];
  const float* bag    = (const float*)d_in[16];

  float* out = (float*)d_out;
  float* ws = (float*)d_ws;
  float* values = ws;                       // 4*1024*128 = 524288 floats
  float* att1v  = ws + 524288;              // 4096
  float* att2v  = ws + 528384;              // 4096
  float* attgv  = ws + 532480;              // 4

  hipLaunchKernelGGL(k_att, dim3(N_ * B_ / 4 + 1), dim3(256), 0, stream,
                     nf, hidden, wa1, ba1, wa2, ba2, gf, wag, bag,
                     att1v, att2v, attgv);
  hipLaunchKernelGGL(k_gemm, dim3(B_ * N_ / 8), dim3(256), 0, stream,
                     nf, hidden, Wm, bm, Wsk, bsk, values, out);
  hipLaunchKernelGGL(k_main, dim3(B_ * N_ / 8), dim3(512), 0, stream,
                     ef, adj, wae, bae, att1v, att2v, attgv, values, out);
}